// Round 2
// baseline (878.586 us; speedup 1.0000x reference)
//
#include <hip/hip_runtime.h>

#define D 128

// ---------------------------------------------------------------- zero ws
__global__ __launch_bounds__(256) void zero_ws_kernel(float* __restrict__ ws, int n) {
    int i = blockIdx.x * blockDim.x + threadIdx.x;
    if (i < n) ws[i] = 0.0f;
}

// ---------------------------------------------------------------- scatter
// One wave (64 lanes) per edge. Lane l handles feature dims {2l, 2l+1}
// via one float2 load (8B/lane -> 512B coalesced per wave), then two fp32
// atomics into nsum[dst].
__global__ __launch_bounds__(256) void scatter_kernel(
        const float* __restrict__ feat,    // [N, D] fp32
        const int* __restrict__ src,
        const int* __restrict__ dst,
        float* __restrict__ nsum,          // [N, D] fp32 accum
        float* __restrict__ deg,           // [N] fp32
        int n_edges) {
    int gid  = blockIdx.x * blockDim.x + threadIdx.x;
    int e    = gid >> 6;
    int lane = gid & 63;
    if (e >= n_edges) return;

    int u = src[e];
    int v = dst[e];

    const float2* fw = (const float2*)(feat + (size_t)u * D);
    float2 w = fw[lane];

    float* o = nsum + (size_t)v * D + lane * 2;
    atomicAdd(o + 0, w.x);
    atomicAdd(o + 1, w.y);
    if (lane == 0) atomicAdd(deg + v, 1.0f);
}

// ---------------------------------------------------------------- epilogue
// 128 threads per block, 4 nodes per block. Thread j owns output dim j for
// all 4 nodes; W rows are read once per block (amortized 4x).
// out[v][j] = b[j] + sum_k f[k]*Ws[k][j] + h[k]*Wn[k][j]
__global__ __launch_bounds__(128) void node_out_kernel(
        const float* __restrict__ feat,    // [N, D] fp32
        const float* __restrict__ nsum,    // [N, D] fp32
        const float* __restrict__ deg,     // [N] fp32
        const float* __restrict__ Ws,      // [D, D] fp32
        const float* __restrict__ Wn,      // [D, D] fp32
        const float* __restrict__ bias,    // [D] fp32
        float* __restrict__ out,           // [N, D] fp32
        int n_nodes) {
    int j  = threadIdx.x;
    int v0 = blockIdx.x * 4;

    __shared__ float fs[4][D];
    __shared__ float hs[4][D];

#pragma unroll
    for (int n = 0; n < 4; ++n) {
        int v = v0 + n;
        if (v < n_nodes) {
            float inv = 1.0f / fmaxf(deg[v], 1.0f);
            fs[n][j] = feat[(size_t)v * D + j];
            hs[n][j] = nsum[(size_t)v * D + j] * inv;
        } else {
            fs[n][j] = 0.0f;
            hs[n][j] = 0.0f;
        }
    }
    __syncthreads();

    float b = bias[j];
    float acc0 = b, acc1 = b, acc2 = b, acc3 = b;

#pragma unroll 4
    for (int k = 0; k < D; ++k) {
        float ws = Ws[k * D + j];
        float wn = Wn[k * D + j];
        acc0 = fmaf(fs[0][k], ws, fmaf(hs[0][k], wn, acc0));
        acc1 = fmaf(fs[1][k], ws, fmaf(hs[1][k], wn, acc1));
        acc2 = fmaf(fs[2][k], ws, fmaf(hs[2][k], wn, acc2));
        acc3 = fmaf(fs[3][k], ws, fmaf(hs[3][k], wn, acc3));
    }

    if (v0 + 0 < n_nodes) out[(size_t)(v0 + 0) * D + j] = acc0;
    if (v0 + 1 < n_nodes) out[(size_t)(v0 + 1) * D + j] = acc1;
    if (v0 + 2 < n_nodes) out[(size_t)(v0 + 2) * D + j] = acc2;
    if (v0 + 3 < n_nodes) out[(size_t)(v0 + 3) * D + j] = acc3;
}

extern "C" void kernel_launch(void* const* d_in, const int* in_sizes, int n_in,
                              void* d_out, int out_size, void* d_ws, size_t ws_size,
                              hipStream_t stream) {
    const float* feat = (const float*)d_in[0];   // fp32 [N,128]
    const int*   src  = (const int*)d_in[1];
    const int*   dst  = (const int*)d_in[2];
    const float* Ws   = (const float*)d_in[3];   // fp32 [128,128]
    const float* Wn   = (const float*)d_in[4];   // fp32 [128,128]
    const float* bias = (const float*)d_in[5];   // fp32 [128]
    float*       out  = (float*)d_out;           // fp32 [N,128]

    const int N = in_sizes[0] / D;
    const int E = in_sizes[1];

    float* nsum = (float*)d_ws;                  // N*D fp32
    float* deg  = nsum + (size_t)N * D;          // N fp32

    // 1) zero accumulators (ws is poisoned 0xAA before every launch)
    int zn = N * D + N;
    zero_ws_kernel<<<(zn + 255) / 256, 256, 0, stream>>>((float*)d_ws, zn);

    // 2) scatter-add along edges: one wave per edge
    long long total_thr = (long long)E * 64;
    int blocks = (int)((total_thr + 255) / 256);
    scatter_kernel<<<blocks, 256, 0, stream>>>(feat, src, dst, nsum, deg, E);

    // 3) per-node normalize + dual matmul + bias (4 nodes per block)
    node_out_kernel<<<(N + 3) / 4, 128, 0, stream>>>(feat, nsum, deg, Ws, Wn, bias, out, N);
}

// Round 3
// 310.245 us; speedup vs baseline: 2.8319x; 2.8319x over previous
//
#include <hip/hip_runtime.h>

#define D 128
#define SCAN_CHUNK 2048   // 256 threads * 8 elements

// ---------------------------------------------------------------- zero ints
__global__ __launch_bounds__(256) void zero_i32(int* __restrict__ p, int n) {
    int i = blockIdx.x * 256 + threadIdx.x;
    if (i < n) p[i] = 0;
}

// ---------------------------------------------------------------- histogram
__global__ __launch_bounds__(256) void hist_kernel(const int* __restrict__ dst,
                                                   int* __restrict__ deg, int E) {
    int e = blockIdx.x * 256 + threadIdx.x;
    if (e < E) atomicAdd(&deg[dst[e]], 1);
}

// ---------------------------------------------------------------- scan phase 1
// Per-chunk (2048 elems) exclusive scan of deg -> rs, chunk total -> bsum[chunk]
__global__ __launch_bounds__(256) void scan1_kernel(const int* __restrict__ deg,
                                                    int* __restrict__ rs,
                                                    int* __restrict__ bsum, int N) {
    __shared__ int lds[256];
    int t = threadIdx.x;
    int base = blockIdx.x * SCAN_CHUNK + t * 8;

    int v[8];
    int tot = 0;
#pragma unroll
    for (int i = 0; i < 8; ++i) {
        int idx = base + i;
        int d = (idx < N) ? deg[idx] : 0;
        v[i] = tot;          // thread-local exclusive prefix
        tot += d;
    }
    lds[t] = tot;
    __syncthreads();
    // Hillis-Steele inclusive scan over 256 thread totals
    for (int off = 1; off < 256; off <<= 1) {
        int add = 0;
        if (t >= off) add = lds[t - off];
        __syncthreads();
        lds[t] += add;
        __syncthreads();
    }
    int inclusive = lds[t];
    int ex = inclusive - tot;   // exclusive prefix of this thread within chunk
#pragma unroll
    for (int i = 0; i < 8; ++i) {
        int idx = base + i;
        if (idx < N) rs[idx] = ex + v[i];
    }
    if (t == 255) bsum[blockIdx.x] = lds[255];
}

// ---------------------------------------------------------------- scan phase 2
// Exclusive scan of the (<=64) chunk totals, single wave via shfl
__global__ __launch_bounds__(64) void scan2_kernel(int* __restrict__ bsum, int nc) {
    int t = threadIdx.x;
    int orig = (t < nc) ? bsum[t] : 0;
    int x = orig;
    for (int off = 1; off < 64; off <<= 1) {
        int y = __shfl_up(x, off);
        if (t >= off) x += y;
    }
    if (t < nc) bsum[t] = x - orig;   // exclusive
}

// ---------------------------------------------------------------- scan phase 3
__global__ __launch_bounds__(256) void scan3_kernel(int* __restrict__ rs,
                                                    const int* __restrict__ bsum, int N) {
    int i = blockIdx.x * 256 + threadIdx.x;
    if (i < N) rs[i] += bsum[i >> 11];   // 2048 = 1<<11
}

// ---------------------------------------------------------------- bucket fill
__global__ __launch_bounds__(256) void fill_kernel(const int* __restrict__ src,
                                                   const int* __restrict__ dst,
                                                   int* __restrict__ cursor,
                                                   const int* __restrict__ rs,
                                                   int* __restrict__ bucket, int E) {
    int e = blockIdx.x * 256 + threadIdx.x;
    if (e < E) {
        int v = dst[e];
        int slot = atomicAdd(&cursor[v], 1);
        bucket[rs[v] + slot] = src[e];
    }
}

// ---------------------------------------------------------------- gather mean
// One wave per node. 2 edges per iteration: half-wave r (32 lanes) reads one
// 512B feature row as float4/lane; fp32 register accumulate; cross-half
// shfl reduce; lanes 0..31 write the mean row (h lives in d_out).
__global__ __launch_bounds__(256) void gather_kernel(const float* __restrict__ feat,
                                                     const int* __restrict__ bucket,
                                                     const int* __restrict__ rs,
                                                     const int* __restrict__ deg,
                                                     float* __restrict__ h, int N) {
    int wid  = (blockIdx.x * 256 + threadIdx.x) >> 6;
    int lane = threadIdx.x & 63;
    if (wid >= N) return;
    int v    = wid;
    int d    = deg[v];
    int base = rs[v];
    int r = lane >> 5;      // which edge of the pair
    int c = lane & 31;      // float4 index within row

    float4 acc = make_float4(0.f, 0.f, 0.f, 0.f);
    for (int i = r; i < d; i += 2) {
        int u = bucket[base + i];
        float4 x = *(const float4*)(feat + (size_t)u * D + c * 4);
        acc.x += x.x; acc.y += x.y; acc.z += x.z; acc.w += x.w;
    }
    acc.x += __shfl_down(acc.x, 32);
    acc.y += __shfl_down(acc.y, 32);
    acc.z += __shfl_down(acc.z, 32);
    acc.w += __shfl_down(acc.w, 32);

    if (r == 0) {
        float inv = (d > 0) ? 1.0f / (float)d : 0.0f;
        float4 o = make_float4(acc.x * inv, acc.y * inv, acc.z * inv, acc.w * inv);
        *(float4*)(h + (size_t)v * D + c * 4) = o;
    }
}

// ---------------------------------------------------------------- epilogue
// 16 nodes per 256-thread block. f,h staged in LDS (broadcast reads).
// Thread (half,j) accumulates 8 nodes for output dim j.
// NOTE: hsrc aliases out (h stored in d_out); each block reads only its own
// rows into LDS before overwriting them — no __restrict__ on those two.
__global__ __launch_bounds__(256) void out_kernel(const float* __restrict__ feat,
                                                  const float* hsrc,
                                                  const float* __restrict__ Ws,
                                                  const float* __restrict__ Wn,
                                                  const float* __restrict__ bias,
                                                  float* out) {
    __shared__ float fs[16 * D];
    __shared__ float hs[16 * D];
    int t  = threadIdx.x;
    int v0 = blockIdx.x * 16;

    const float4* f4p = (const float4*)(feat + (size_t)v0 * D);
    const float4* h4p = (const float4*)(hsrc + (size_t)v0 * D);
    float4* fd = (float4*)fs;
    float4* hd = (float4*)hs;
    fd[t]       = f4p[t];
    fd[t + 256] = f4p[t + 256];
    hd[t]       = h4p[t];
    hd[t + 256] = h4p[t + 256];
    __syncthreads();

    int j    = t & 127;
    int half = t >> 7;
    const float* f0 = fs + half * 8 * D;
    const float* h0 = hs + half * 8 * D;

    float b = bias[j];
    float acc[8];
#pragma unroll
    for (int n = 0; n < 8; ++n) acc[n] = b;

    for (int k0 = 0; k0 < D; k0 += 4) {
        float w_s[4], w_n[4];
#pragma unroll
        for (int q = 0; q < 4; ++q) {
            w_s[q] = Ws[(k0 + q) * D + j];
            w_n[q] = Wn[(k0 + q) * D + j];
        }
#pragma unroll
        for (int n = 0; n < 8; ++n) {
            float4 f4 = *(const float4*)(f0 + n * D + k0);
            float4 h4 = *(const float4*)(h0 + n * D + k0);
            acc[n] = fmaf(f4.x, w_s[0], fmaf(h4.x, w_n[0], acc[n]));
            acc[n] = fmaf(f4.y, w_s[1], fmaf(h4.y, w_n[1], acc[n]));
            acc[n] = fmaf(f4.z, w_s[2], fmaf(h4.z, w_n[2], acc[n]));
            acc[n] = fmaf(f4.w, w_s[3], fmaf(h4.w, w_n[3], acc[n]));
        }
    }

#pragma unroll
    for (int n = 0; n < 8; ++n)
        out[(size_t)(v0 + half * 8 + n) * D + j] = acc[n];
}

extern "C" void kernel_launch(void* const* d_in, const int* in_sizes, int n_in,
                              void* d_out, int out_size, void* d_ws, size_t ws_size,
                              hipStream_t stream) {
    const float* feat = (const float*)d_in[0];
    const int*   src  = (const int*)d_in[1];
    const int*   dst  = (const int*)d_in[2];
    const float* Ws   = (const float*)d_in[3];
    const float* Wn   = (const float*)d_in[4];
    const float* bias = (const float*)d_in[5];
    float*       out  = (float*)d_out;

    const int N = in_sizes[0] / D;
    const int E = in_sizes[1];
    const int nchunks = (N + SCAN_CHUNK - 1) / SCAN_CHUNK;

    // ws layout (ints): deg[N] | cursor[N] | rs[N] | bsum[64] | bucket[E]
    int* deg    = (int*)d_ws;
    int* cursor = deg + N;
    int* rs     = cursor + N;
    int* bsum   = rs + N;
    int* bucket = bsum + 64;

    float* h = out;   // h_mean staged in d_out, overwritten by out_kernel

    // 1) zero deg + cursor (contiguous)
    zero_i32<<<(2 * N + 255) / 256, 256, 0, stream>>>(deg, 2 * N);
    // 2) in-degree histogram
    hist_kernel<<<(E + 255) / 256, 256, 0, stream>>>(dst, deg, E);
    // 3) exclusive scan deg -> rs
    scan1_kernel<<<nchunks, 256, 0, stream>>>(deg, rs, bsum, N);
    scan2_kernel<<<1, 64, 0, stream>>>(bsum, nchunks);
    scan3_kernel<<<(N + 255) / 256, 256, 0, stream>>>(rs, bsum, N);
    // 4) fill CSR buckets with edge sources
    fill_kernel<<<(E + 255) / 256, 256, 0, stream>>>(src, dst, cursor, rs, bucket, E);
    // 5) gather + mean (one wave per node), h -> d_out
    gather_kernel<<<(N * 64 + 255) / 256, 256, 0, stream>>>(feat, bucket, rs, deg, h, N);
    // 6) fused dual-matmul epilogue, in-place over d_out
    out_kernel<<<N / 16, 256, 0, stream>>>(feat, h, Ws, Wn, bias, out);
}

// Round 4
// 271.349 us; speedup vs baseline: 3.2378x; 1.1433x over previous
//
#include <hip/hip_runtime.h>

#define D 128
#define SCAN_CHUNK 2048   // 256 threads * 8 elements

typedef __attribute__((ext_vector_type(8))) short bf16x8;
typedef __attribute__((ext_vector_type(4))) float f32x4;

__device__ __forceinline__ unsigned short f2bf(float f) {
    union { float f; unsigned int u; } c;
    c.f = f;
    unsigned int lsb = (c.u >> 16) & 1u;
    c.u += 0x7fffu + lsb;
    return (unsigned short)(c.u >> 16);
}

// ---------------------------------------------------------------- zero ints
__global__ __launch_bounds__(256) void zero_i32(int* __restrict__ p, int n) {
    int i = blockIdx.x * 256 + threadIdx.x;
    if (i < n) p[i] = 0;
}

// ---------------------------------------------------------------- histogram
__global__ __launch_bounds__(256) void hist_kernel(const int* __restrict__ dst,
                                                   int* __restrict__ deg, int E) {
    int e = blockIdx.x * 256 + threadIdx.x;
    if (e < E) atomicAdd(&deg[dst[e]], 1);
}

// ---------------------------------------------------------------- scan phase 1
__global__ __launch_bounds__(256) void scan1_kernel(const int* __restrict__ deg,
                                                    int* __restrict__ rs,
                                                    int* __restrict__ bsum, int N) {
    __shared__ int lds[256];
    int t = threadIdx.x;
    int base = blockIdx.x * SCAN_CHUNK + t * 8;

    int v[8];
    int tot = 0;
#pragma unroll
    for (int i = 0; i < 8; ++i) {
        int idx = base + i;
        int d = (idx < N) ? deg[idx] : 0;
        v[i] = tot;
        tot += d;
    }
    lds[t] = tot;
    __syncthreads();
    for (int off = 1; off < 256; off <<= 1) {
        int add = 0;
        if (t >= off) add = lds[t - off];
        __syncthreads();
        lds[t] += add;
        __syncthreads();
    }
    int inclusive = lds[t];
    int ex = inclusive - tot;
#pragma unroll
    for (int i = 0; i < 8; ++i) {
        int idx = base + i;
        if (idx < N) rs[idx] = ex + v[i];
    }
    if (t == 255) bsum[blockIdx.x] = lds[255];
}

// ---------------------------------------------------------------- scan phase 2
__global__ __launch_bounds__(64) void scan2_kernel(int* __restrict__ bsum, int nc) {
    int t = threadIdx.x;
    int orig = (t < nc) ? bsum[t] : 0;
    int x = orig;
    for (int off = 1; off < 64; off <<= 1) {
        int y = __shfl_up(x, off);
        if (t >= off) x += y;
    }
    if (t < nc) bsum[t] = x - orig;
}

// ---------------------------------------------------------------- scan phase 3
__global__ __launch_bounds__(256) void scan3_kernel(int* __restrict__ rs,
                                                    const int* __restrict__ bsum, int N) {
    int i = blockIdx.x * 256 + threadIdx.x;
    if (i < N) rs[i] += bsum[i >> 11];
}

// ---------------------------------------------------------------- bucket fill
__global__ __launch_bounds__(256) void fill_kernel(const int* __restrict__ src,
                                                   const int* __restrict__ dst,
                                                   int* __restrict__ cursor,
                                                   const int* __restrict__ rs,
                                                   int* __restrict__ bucket, int E) {
    int e = blockIdx.x * 256 + threadIdx.x;
    if (e < E) {
        int v = dst[e];
        int slot = atomicAdd(&cursor[v], 1);
        bucket[rs[v] + slot] = src[e];
    }
}

// ---------------------------------------------------------------- gather mean
__global__ __launch_bounds__(256) void gather_kernel(const float* __restrict__ feat,
                                                     const int* __restrict__ bucket,
                                                     const int* __restrict__ rs,
                                                     const int* __restrict__ deg,
                                                     float* __restrict__ h, int N) {
    int wid  = (blockIdx.x * 256 + threadIdx.x) >> 6;
    int lane = threadIdx.x & 63;
    if (wid >= N) return;
    int v    = wid;
    int d    = deg[v];
    int base = rs[v];
    int r = lane >> 5;
    int c = lane & 31;

    float4 acc = make_float4(0.f, 0.f, 0.f, 0.f);
    for (int i = r; i < d; i += 2) {
        int u = bucket[base + i];
        float4 x = *(const float4*)(feat + (size_t)u * D + c * 4);
        acc.x += x.x; acc.y += x.y; acc.z += x.z; acc.w += x.w;
    }
    acc.x += __shfl_down(acc.x, 32);
    acc.y += __shfl_down(acc.y, 32);
    acc.z += __shfl_down(acc.z, 32);
    acc.w += __shfl_down(acc.w, 32);

    if (r == 0) {
        float inv = (d > 0) ? 1.0f / (float)d : 0.0f;
        float4 o = make_float4(acc.x * inv, acc.y * inv, acc.z * inv, acc.w * inv);
        *(float4*)(h + (size_t)v * D + c * 4) = o;
    }
}

// ---------------------------------------------------------------- MFMA epilogue
// out[M=50000,128] = X[M,256] @ Wcat[256,128] + b, X = [f | h], Wcat = [Ws;Wn].
// Block: 256 threads = 4 waves; M-tile = 64 rows; bf16 16x16x32 MFMA.
// LDS: Xs[64][264] + Wt[128][264] bf16 = 101 KB -> 1 block/CU.
// Row stride 264 shorts = 528 B = 33*16 B (keeps b128 alignment, 2-way-free banks).
// NOTE: hsrc aliases out (h staged in d_out); each block reads only its own
// rows into LDS (before any store) — no cross-block aliasing.
#define KX 256
#define XP 8
__global__ __launch_bounds__(256) void out_mfma_kernel(const float* __restrict__ feat,
                                                       const float* hsrc,
                                                       const float* __restrict__ Ws,
                                                       const float* __restrict__ Wn,
                                                       const float* __restrict__ bias,
                                                       float* out, int N) {
    __shared__ short Xs[64][KX + XP];
    __shared__ short Wt[128][KX + XP];

    int t  = threadIdx.x;
    int v0 = blockIdx.x * 64;

    // ---- stage Wt[n][k] = Wcat[k][n] as bf16 (coalesced global reads) ----
    {
        int n    = t & 127;
        int half = t >> 7;                 // k-range [half*128, half*128+128)
        const float* Wsrc = half ? Wn : Ws;
#pragma unroll
        for (int j = 0; j < 16; ++j) {
            short pk[8];
#pragma unroll
            for (int i = 0; i < 8; ++i) {
                int kk = j * 8 + i;
                pk[i] = (short)f2bf(Wsrc[kk * D + n]);
            }
            *(bf16x8*)&Wt[n][half * 128 + j * 8] =
                *(const bf16x8*)pk;
        }
    }

    // ---- stage Xs[m][k]: k<128 -> f[v0+m], k>=128 -> h[v0+m] ----
    {
        int m = t >> 2;
        int q = t & 3;                     // 64-element k-chunk
        int v = v0 + m;
        const float* srcp = (q < 2) ? (feat + (size_t)v * D + (q & 1) * 64)
                                    : (hsrc + (size_t)v * D + (q & 1) * 64);
        int kbase = q * 64;
        if (v < N) {
#pragma unroll
            for (int j = 0; j < 8; ++j) {
                float4 a = *(const float4*)(srcp + j * 8);
                float4 b = *(const float4*)(srcp + j * 8 + 4);
                short pk[8];
                pk[0] = (short)f2bf(a.x); pk[1] = (short)f2bf(a.y);
                pk[2] = (short)f2bf(a.z); pk[3] = (short)f2bf(a.w);
                pk[4] = (short)f2bf(b.x); pk[5] = (short)f2bf(b.y);
                pk[6] = (short)f2bf(b.z); pk[7] = (short)f2bf(b.w);
                *(bf16x8*)&Xs[m][kbase + j * 8] = *(const bf16x8*)pk;
            }
        } else {
            short z[8] = {0, 0, 0, 0, 0, 0, 0, 0};
#pragma unroll
            for (int j = 0; j < 8; ++j)
                *(bf16x8*)&Xs[m][kbase + j * 8] = *(const bf16x8*)z;
        }
    }
    __syncthreads();

    // ---- MFMA main loop: wave w owns rows [w*16, w*16+16) x all 128 cols ----
    int w    = t >> 6;
    int lane = t & 63;
    int lo16 = lane & 15;
    int quad = lane >> 4;

    f32x4 acc[8];
#pragma unroll
    for (int nt = 0; nt < 8; ++nt) acc[nt] = (f32x4){0.f, 0.f, 0.f, 0.f};

#pragma unroll
    for (int ks = 0; ks < 8; ++ks) {
        bf16x8 a = *(const bf16x8*)&Xs[w * 16 + lo16][ks * 32 + quad * 8];
#pragma unroll
        for (int nt = 0; nt < 8; ++nt) {
            bf16x8 b = *(const bf16x8*)&Wt[nt * 16 + lo16][ks * 32 + quad * 8];
            acc[nt] = __builtin_amdgcn_mfma_f32_16x16x32_bf16(a, b, acc[nt], 0, 0, 0);
        }
    }

    // ---- epilogue: C/D layout col=lane&15, row=quad*4+reg; add bias ----
#pragma unroll
    for (int nt = 0; nt < 8; ++nt) {
        int n = nt * 16 + lo16;
        float bv = bias[n];
#pragma unroll
        for (int r = 0; r < 4; ++r) {
            int row = v0 + w * 16 + quad * 4 + r;
            if (row < N) out[(size_t)row * D + n] = acc[nt][r] + bv;
        }
    }
}

extern "C" void kernel_launch(void* const* d_in, const int* in_sizes, int n_in,
                              void* d_out, int out_size, void* d_ws, size_t ws_size,
                              hipStream_t stream) {
    const float* feat = (const float*)d_in[0];
    const int*   src  = (const int*)d_in[1];
    const int*   dst  = (const int*)d_in[2];
    const float* Ws   = (const float*)d_in[3];
    const float* Wn   = (const float*)d_in[4];
    const float* bias = (const float*)d_in[5];
    float*       out  = (float*)d_out;

    const int N = in_sizes[0] / D;
    const int E = in_sizes[1];
    const int nchunks = (N + SCAN_CHUNK - 1) / SCAN_CHUNK;

    // ws layout (ints): deg[N] | cursor[N] | rs[N] | bsum[64] | bucket[E]
    int* deg    = (int*)d_ws;
    int* cursor = deg + N;
    int* rs     = cursor + N;
    int* bsum   = rs + N;
    int* bucket = bsum + 64;

    float* h = out;   // h_mean staged in d_out, consumed in-tile by out_mfma

    zero_i32<<<(2 * N + 255) / 256, 256, 0, stream>>>(deg, 2 * N);
    hist_kernel<<<(E + 255) / 256, 256, 0, stream>>>(dst, deg, E);
    scan1_kernel<<<nchunks, 256, 0, stream>>>(deg, rs, bsum, N);
    scan2_kernel<<<1, 64, 0, stream>>>(bsum, nchunks);
    scan3_kernel<<<(N + 255) / 256, 256, 0, stream>>>(rs, bsum, N);
    fill_kernel<<<(E + 255) / 256, 256, 0, stream>>>(src, dst, cursor, rs, bucket, E);
    gather_kernel<<<(N * 64 + 255) / 256, 256, 0, stream>>>(feat, bucket, rs, deg, h, N);
    out_mfma_kernel<<<(N + 63) / 64, 256, 0, stream>>>(feat, h, Ws, Wn, bias, out, N);
}

// Round 5
// 270.023 us; speedup vs baseline: 3.2537x; 1.0049x over previous
//
#include <hip/hip_runtime.h>

#define D 128
#define SCAN_CHUNK 2048   // 256 threads * 8 elements

typedef __attribute__((ext_vector_type(8))) short bf16x8;
typedef __attribute__((ext_vector_type(4))) float f32x4;

__device__ __forceinline__ unsigned short f2bf(float f) {
    union { float f; unsigned int u; } c;
    c.f = f;
    unsigned int lsb = (c.u >> 16) & 1u;
    c.u += 0x7fffu + lsb;
    return (unsigned short)(c.u >> 16);
}

__device__ __forceinline__ float bf2f(unsigned short h) {
    union { unsigned int u; float f; } c;
    c.u = ((unsigned int)h) << 16;
    return c.f;
}

// ---------------------------------------------------------------- zero ints
__global__ __launch_bounds__(256) void zero_i32(int* __restrict__ p, int n) {
    int i = blockIdx.x * 256 + threadIdx.x;
    if (i < n) p[i] = 0;
}

// ---------------------------------------------------------------- cast feat -> bf16
// One thread per 8 elements: 32B read, 16B write.
__global__ __launch_bounds__(256) void cast_feat_kernel(const float* __restrict__ feat,
                                                        unsigned short* __restrict__ fb,
                                                        int n8) {
    int i = blockIdx.x * 256 + threadIdx.x;
    if (i >= n8) return;
    const float4* s = (const float4*)(feat + (size_t)i * 8);
    float4 a = s[0];
    float4 b = s[1];
    unsigned short pk[8];
    pk[0] = f2bf(a.x); pk[1] = f2bf(a.y); pk[2] = f2bf(a.z); pk[3] = f2bf(a.w);
    pk[4] = f2bf(b.x); pk[5] = f2bf(b.y); pk[6] = f2bf(b.z); pk[7] = f2bf(b.w);
    *(bf16x8*)(fb + (size_t)i * 8) = *(const bf16x8*)pk;
}

// ---------------------------------------------------------------- histogram
__global__ __launch_bounds__(256) void hist_kernel(const int* __restrict__ dst,
                                                   int* __restrict__ deg, int E) {
    int e = blockIdx.x * 256 + threadIdx.x;
    if (e < E) atomicAdd(&deg[dst[e]], 1);
}

// ---------------------------------------------------------------- scan phase 1
__global__ __launch_bounds__(256) void scan1_kernel(const int* __restrict__ deg,
                                                    int* __restrict__ rs,
                                                    int* __restrict__ bsum, int N) {
    __shared__ int lds[256];
    int t = threadIdx.x;
    int base = blockIdx.x * SCAN_CHUNK + t * 8;

    int v[8];
    int tot = 0;
#pragma unroll
    for (int i = 0; i < 8; ++i) {
        int idx = base + i;
        int d = (idx < N) ? deg[idx] : 0;
        v[i] = tot;
        tot += d;
    }
    lds[t] = tot;
    __syncthreads();
    for (int off = 1; off < 256; off <<= 1) {
        int add = 0;
        if (t >= off) add = lds[t - off];
        __syncthreads();
        lds[t] += add;
        __syncthreads();
    }
    int inclusive = lds[t];
    int ex = inclusive - tot;
#pragma unroll
    for (int i = 0; i < 8; ++i) {
        int idx = base + i;
        if (idx < N) rs[idx] = ex + v[i];
    }
    if (t == 255) bsum[blockIdx.x] = lds[255];
}

// ---------------------------------------------------------------- scan phase 2
__global__ __launch_bounds__(64) void scan2_kernel(int* __restrict__ bsum, int nc) {
    int t = threadIdx.x;
    int orig = (t < nc) ? bsum[t] : 0;
    int x = orig;
    for (int off = 1; off < 64; off <<= 1) {
        int y = __shfl_up(x, off);
        if (t >= off) x += y;
    }
    if (t < nc) bsum[t] = x - orig;
}

// ---------------------------------------------------------------- scan phase 3
__global__ __launch_bounds__(256) void scan3_kernel(int* __restrict__ rs,
                                                    const int* __restrict__ bsum, int N) {
    int i = blockIdx.x * 256 + threadIdx.x;
    if (i < N) rs[i] += bsum[i >> 11];
}

// ---------------------------------------------------------------- bucket fill
__global__ __launch_bounds__(256) void fill_kernel(const int* __restrict__ src,
                                                   const int* __restrict__ dst,
                                                   int* __restrict__ cursor,
                                                   const int* __restrict__ rs,
                                                   int* __restrict__ bucket, int E) {
    int e = blockIdx.x * 256 + threadIdx.x;
    if (e < E) {
        int v = dst[e];
        int slot = atomicAdd(&cursor[v], 1);
        bucket[rs[v] + slot] = src[e];
    }
}

// ---------------------------------------------------------------- gather mean (bf16 rows)
// One wave per node; 2 edges per iteration. Half-wave r (32 lanes) reads one
// 256B bf16 row: lane loads ushort4 (8B) = dims [4c, 4c+4), fp32 accumulate,
// cross-half shfl reduce, lanes 0..31 write the fp32 mean row (h in d_out).
__global__ __launch_bounds__(256) void gather_kernel(const unsigned short* __restrict__ fb,
                                                     const int* __restrict__ bucket,
                                                     const int* __restrict__ rs,
                                                     const int* __restrict__ deg,
                                                     float* __restrict__ h, int N) {
    int wid  = (blockIdx.x * 256 + threadIdx.x) >> 6;
    int lane = threadIdx.x & 63;
    if (wid >= N) return;
    int v    = wid;
    int d    = deg[v];
    int base = rs[v];
    int r = lane >> 5;
    int c = lane & 31;

    float a0 = 0.f, a1 = 0.f, a2 = 0.f, a3 = 0.f;
    for (int i = r; i < d; i += 2) {
        int u = bucket[base + i];
        uint2 x = *(const uint2*)(fb + (size_t)u * D + c * 4);
        a0 += bf2f((unsigned short)(x.x & 0xffffu));
        a1 += bf2f((unsigned short)(x.x >> 16));
        a2 += bf2f((unsigned short)(x.y & 0xffffu));
        a3 += bf2f((unsigned short)(x.y >> 16));
    }
    a0 += __shfl_down(a0, 32);
    a1 += __shfl_down(a1, 32);
    a2 += __shfl_down(a2, 32);
    a3 += __shfl_down(a3, 32);

    if (r == 0) {
        float inv = (d > 0) ? 1.0f / (float)d : 0.0f;
        float4 o = make_float4(a0 * inv, a1 * inv, a2 * inv, a3 * inv);
        *(float4*)(h + (size_t)v * D + c * 4) = o;
    }
}

// ---------------------------------------------------------------- MFMA epilogue
// out[M,128] = X[M,256] @ Wcat[256,128] + b, X = [f | h], Wcat = [Ws;Wn].
// f-tile staged directly from bf16 table (no convert); h converted fp32->bf16.
// LDS: Xs[64][264] + Wt[128][264] bf16 = 101 KB -> 1 block/CU.
// NOTE: hsrc aliases out (h staged in d_out); each block reads only its own
// rows into LDS before storing — no cross-block aliasing.
#define KX 256
#define XP 8
__global__ __launch_bounds__(256) void out_mfma_kernel(const unsigned short* __restrict__ fb,
                                                       const float* hsrc,
                                                       const float* __restrict__ Ws,
                                                       const float* __restrict__ Wn,
                                                       const float* __restrict__ bias,
                                                       float* out, int N) {
    __shared__ short Xs[64][KX + XP];
    __shared__ short Wt[128][KX + XP];

    int t  = threadIdx.x;
    int v0 = blockIdx.x * 64;

    // ---- stage Wt[n][k] = Wcat[k][n] as bf16 (coalesced global reads) ----
    {
        int n    = t & 127;
        int half = t >> 7;                 // k-range [half*128, half*128+128)
        const float* Wsrc = half ? Wn : Ws;
#pragma unroll
        for (int j = 0; j < 16; ++j) {
            short pk[8];
#pragma unroll
            for (int i = 0; i < 8; ++i) {
                int kk = j * 8 + i;
                pk[i] = (short)f2bf(Wsrc[kk * D + n]);
            }
            *(bf16x8*)&Wt[n][half * 128 + j * 8] = *(const bf16x8*)pk;
        }
    }

    // ---- stage Xs[m][k]: k<128 -> fb[v0+m] (copy), k>=128 -> h (convert) ----
    {
        int m = t >> 2;
        int q = t & 3;                     // 64-element k-chunk
        int v = v0 + m;
        int kbase = q * 64;
        if (v < N) {
            if (q < 2) {
                const unsigned short* sp = fb + (size_t)v * D + (q & 1) * 64;
#pragma unroll
                for (int j = 0; j < 8; ++j)
                    *(bf16x8*)&Xs[m][kbase + j * 8] = *(const bf16x8*)(sp + j * 8);
            } else {
                const float* sp = hsrc + (size_t)v * D + (q & 1) * 64;
#pragma unroll
                for (int j = 0; j < 8; ++j) {
                    float4 a = *(const float4*)(sp + j * 8);
                    float4 b = *(const float4*)(sp + j * 8 + 4);
                    short pk[8];
                    pk[0] = (short)f2bf(a.x); pk[1] = (short)f2bf(a.y);
                    pk[2] = (short)f2bf(a.z); pk[3] = (short)f2bf(a.w);
                    pk[4] = (short)f2bf(b.x); pk[5] = (short)f2bf(b.y);
                    pk[6] = (short)f2bf(b.z); pk[7] = (short)f2bf(b.w);
                    *(bf16x8*)&Xs[m][kbase + j * 8] = *(const bf16x8*)pk;
                }
            }
        } else {
            short z[8] = {0, 0, 0, 0, 0, 0, 0, 0};
#pragma unroll
            for (int j = 0; j < 8; ++j)
                *(bf16x8*)&Xs[m][kbase + j * 8] = *(const bf16x8*)z;
        }
    }
    __syncthreads();

    // ---- MFMA main loop: wave w owns rows [w*16, w*16+16) x all 128 cols ----
    int w    = t >> 6;
    int lane = t & 63;
    int lo16 = lane & 15;
    int quad = lane >> 4;

    f32x4 acc[8];
#pragma unroll
    for (int nt = 0; nt < 8; ++nt) acc[nt] = (f32x4){0.f, 0.f, 0.f, 0.f};

#pragma unroll
    for (int ks = 0; ks < 8; ++ks) {
        bf16x8 a = *(const bf16x8*)&Xs[w * 16 + lo16][ks * 32 + quad * 8];
#pragma unroll
        for (int nt = 0; nt < 8; ++nt) {
            bf16x8 b = *(const bf16x8*)&Wt[nt * 16 + lo16][ks * 32 + quad * 8];
            acc[nt] = __builtin_amdgcn_mfma_f32_16x16x32_bf16(a, b, acc[nt], 0, 0, 0);
        }
    }

    // ---- epilogue: C/D layout col=lane&15, row=quad*4+reg; add bias ----
#pragma unroll
    for (int nt = 0; nt < 8; ++nt) {
        int n = nt * 16 + lo16;
        float bv = bias[n];
#pragma unroll
        for (int r = 0; r < 4; ++r) {
            int row = v0 + w * 16 + quad * 4 + r;
            if (row < N) out[(size_t)row * D + n] = acc[nt][r] + bv;
        }
    }
}

extern "C" void kernel_launch(void* const* d_in, const int* in_sizes, int n_in,
                              void* d_out, int out_size, void* d_ws, size_t ws_size,
                              hipStream_t stream) {
    const float* feat = (const float*)d_in[0];
    const int*   src  = (const int*)d_in[1];
    const int*   dst  = (const int*)d_in[2];
    const float* Ws   = (const float*)d_in[3];
    const float* Wn   = (const float*)d_in[4];
    const float* bias = (const float*)d_in[5];
    float*       out  = (float*)d_out;

    const int N = in_sizes[0] / D;
    const int E = in_sizes[1];
    const int nchunks = (N + SCAN_CHUNK - 1) / SCAN_CHUNK;

    // ws layout: deg[N] | cursor[N] | rs[N] | bsum[64] | bucket[E] | pad | fb[N*D bf16]
    int* deg    = (int*)d_ws;
    int* cursor = deg + N;
    int* rs     = cursor + N;
    int* bsum   = rs + N;
    int* bucket = bsum + 64;
    size_t int_count = (size_t)(3 * N + 64 + E);
    int_count = (int_count + 7) & ~(size_t)7;            // 16B-align what follows
    unsigned short* fb = (unsigned short*)((int*)d_ws + int_count);

    float* h = out;   // h_mean staged fp32 in d_out, consumed in-tile by out_mfma

    zero_i32<<<(2 * N + 255) / 256, 256, 0, stream>>>(deg, 2 * N);
    cast_feat_kernel<<<(N * D / 8 + 255) / 256, 256, 0, stream>>>(feat, fb, N * D / 8);
    hist_kernel<<<(E + 255) / 256, 256, 0, stream>>>(dst, deg, E);
    scan1_kernel<<<nchunks, 256, 0, stream>>>(deg, rs, bsum, N);
    scan2_kernel<<<1, 64, 0, stream>>>(bsum, nchunks);
    scan3_kernel<<<(N + 255) / 256, 256, 0, stream>>>(rs, bsum, N);
    fill_kernel<<<(E + 255) / 256, 256, 0, stream>>>(src, dst, cursor, rs, bucket, E);
    gather_kernel<<<(N * 64 + 255) / 256, 256, 0, stream>>>(fb, bucket, rs, deg, h, N);
    out_mfma_kernel<<<(N + 63) / 64, 256, 0, stream>>>(fb, h, Ws, Wn, bias, out, N);
}

// Round 6
// 254.093 us; speedup vs baseline: 3.4577x; 1.0627x over previous
//
#include <hip/hip_runtime.h>

#define D 128
#define SCAN_CHUNK 2048   // 256 threads * 8 elements

typedef __attribute__((ext_vector_type(8))) short bf16x8;
typedef __attribute__((ext_vector_type(4))) float f32x4;

__device__ __forceinline__ unsigned short f2bf(float f) {
    union { float f; unsigned int u; } c;
    c.f = f;
    unsigned int lsb = (c.u >> 16) & 1u;
    c.u += 0x7fffu + lsb;
    return (unsigned short)(c.u >> 16);
}

__device__ __forceinline__ float bf_lo(unsigned int x) {
    union { unsigned int u; float f; } c;
    c.u = x << 16;
    return c.f;
}
__device__ __forceinline__ float bf_hi(unsigned int x) {
    union { unsigned int u; float f; } c;
    c.u = x & 0xffff0000u;
    return c.f;
}

// ---------------------------------------------------------------- zero ints
__global__ __launch_bounds__(256) void zero_i32(int* __restrict__ p, int n) {
    int i = blockIdx.x * 256 + threadIdx.x;
    if (i < n) p[i] = 0;
}

// ---------------------------------------------------------------- cast feat -> bf16
__global__ __launch_bounds__(256) void cast_feat_kernel(const float* __restrict__ feat,
                                                        unsigned short* __restrict__ fb,
                                                        int n8) {
    int i = blockIdx.x * 256 + threadIdx.x;
    if (i >= n8) return;
    const float4* s = (const float4*)(feat + (size_t)i * 8);
    float4 a = s[0];
    float4 b = s[1];
    unsigned short pk[8];
    pk[0] = f2bf(a.x); pk[1] = f2bf(a.y); pk[2] = f2bf(a.z); pk[3] = f2bf(a.w);
    pk[4] = f2bf(b.x); pk[5] = f2bf(b.y); pk[6] = f2bf(b.z); pk[7] = f2bf(b.w);
    *(bf16x8*)(fb + (size_t)i * 8) = *(const bf16x8*)pk;
}

// ---------------------------------------------------------------- histogram
__global__ __launch_bounds__(256) void hist_kernel(const int* __restrict__ dst,
                                                   int* __restrict__ deg, int E) {
    int e = blockIdx.x * 256 + threadIdx.x;
    if (e < E) atomicAdd(&deg[dst[e]], 1);
}

// ---------------------------------------------------------------- scan phase 1
__global__ __launch_bounds__(256) void scan1_kernel(const int* __restrict__ deg,
                                                    int* __restrict__ rs,
                                                    int* __restrict__ bsum, int N) {
    __shared__ int lds[256];
    int t = threadIdx.x;
    int base = blockIdx.x * SCAN_CHUNK + t * 8;

    int v[8];
    int tot = 0;
#pragma unroll
    for (int i = 0; i < 8; ++i) {
        int idx = base + i;
        int d = (idx < N) ? deg[idx] : 0;
        v[i] = tot;
        tot += d;
    }
    lds[t] = tot;
    __syncthreads();
    for (int off = 1; off < 256; off <<= 1) {
        int add = 0;
        if (t >= off) add = lds[t - off];
        __syncthreads();
        lds[t] += add;
        __syncthreads();
    }
    int inclusive = lds[t];
    int ex = inclusive - tot;
#pragma unroll
    for (int i = 0; i < 8; ++i) {
        int idx = base + i;
        if (idx < N) rs[idx] = ex + v[i];
    }
    if (t == 255) bsum[blockIdx.x] = lds[255];
}

// ---------------------------------------------------------------- scan phase 2
__global__ __launch_bounds__(64) void scan2_kernel(int* __restrict__ bsum, int nc) {
    int t = threadIdx.x;
    int orig = (t < nc) ? bsum[t] : 0;
    int x = orig;
    for (int off = 1; off < 64; off <<= 1) {
        int y = __shfl_up(x, off);
        if (t >= off) x += y;
    }
    if (t < nc) bsum[t] = x - orig;
}

// ---------------------------------------------------------------- scan phase 3
__global__ __launch_bounds__(256) void scan3_kernel(int* __restrict__ rs,
                                                    const int* __restrict__ bsum, int N) {
    int i = blockIdx.x * 256 + threadIdx.x;
    if (i < N) rs[i] += bsum[i >> 11];
}

// ---------------------------------------------------------------- bucket fill
__global__ __launch_bounds__(256) void fill_kernel(const int* __restrict__ src,
                                                   const int* __restrict__ dst,
                                                   int* __restrict__ cursor,
                                                   const int* __restrict__ rs,
                                                   int* __restrict__ bucket, int E) {
    int e = blockIdx.x * 256 + threadIdx.x;
    if (e < E) {
        int v = dst[e];
        int slot = atomicAdd(&cursor[v], 1);
        bucket[rs[v] + slot] = src[e];
    }
}

// ---------------------------------------------------------------- gather mean (bf16 rows)
// One wave per node; 4 edges in flight per iteration. Wave = 4 groups x 16
// lanes; group g reads edge (i+g)'s full 256B row, lane c covering dims
// [8c, 8c+8) via one 16B ushort8 load. Next iteration's bucket index is
// prefetched before the accumulate to overlap latency. Cross-group reduce
// via shfl_xor(16/32); group 0 writes the fp32 mean row (h lives in d_out).
__global__ __launch_bounds__(256) void gather_kernel(const unsigned short* __restrict__ fb,
                                                     const int* __restrict__ bucket,
                                                     const int* __restrict__ rs,
                                                     const int* __restrict__ deg,
                                                     float* __restrict__ h, int N) {
    int wid  = (blockIdx.x * 256 + threadIdx.x) >> 6;
    int lane = threadIdx.x & 63;
    if (wid >= N) return;
    int v    = wid;
    int d    = deg[v];
    int base = rs[v];
    int g = lane >> 4;      // edge group 0..3
    int c = lane & 15;      // ushort8 index within row

    float acc[8];
#pragma unroll
    for (int j = 0; j < 8; ++j) acc[j] = 0.f;

    int u = (g < d) ? bucket[base + g] : -1;
    for (int i = g; i < d; i += 4) {
        int inext = i + 4;
        int unext = (inext < d) ? bucket[base + inext] : -1;   // prefetch
        const unsigned int* rp = (const unsigned int*)(fb + (size_t)u * D + c * 8);
        uint4 x = *(const uint4*)rp;                            // 16B = 8 bf16
        acc[0] += bf_lo(x.x); acc[1] += bf_hi(x.x);
        acc[2] += bf_lo(x.y); acc[3] += bf_hi(x.y);
        acc[4] += bf_lo(x.z); acc[5] += bf_hi(x.z);
        acc[6] += bf_lo(x.w); acc[7] += bf_hi(x.w);
        u = unext;
    }

#pragma unroll
    for (int j = 0; j < 8; ++j) {
        acc[j] += __shfl_xor(acc[j], 16);
        acc[j] += __shfl_xor(acc[j], 32);
    }

    if (g == 0) {
        float inv = (d > 0) ? 1.0f / (float)d : 0.0f;
        float4 o0 = make_float4(acc[0] * inv, acc[1] * inv, acc[2] * inv, acc[3] * inv);
        float4 o1 = make_float4(acc[4] * inv, acc[5] * inv, acc[6] * inv, acc[7] * inv);
        float* op = h + (size_t)v * D + c * 8;
        *(float4*)op = o0;
        *(float4*)(op + 4) = o1;
    }
}

// ---------------------------------------------------------------- MFMA epilogue
// out[M,128] = X[M,256] @ Wcat[256,128] + b, X = [f | h], Wcat = [Ws;Wn].
// LDS: Xs[64][264] + Wt[128][264] bf16 = 101 KB -> 1 block/CU.
// NOTE: hsrc aliases out (h staged in d_out); each block reads only its own
// rows into LDS before storing — no cross-block aliasing.
#define KX 256
#define XP 8
__global__ __launch_bounds__(256) void out_mfma_kernel(const unsigned short* __restrict__ fb,
                                                       const float* hsrc,
                                                       const float* __restrict__ Ws,
                                                       const float* __restrict__ Wn,
                                                       const float* __restrict__ bias,
                                                       float* out, int N) {
    __shared__ short Xs[64][KX + XP];
    __shared__ short Wt[128][KX + XP];

    int t  = threadIdx.x;
    int v0 = blockIdx.x * 64;

    // ---- stage Wt[n][k] = Wcat[k][n] as bf16 (coalesced global reads) ----
    {
        int n    = t & 127;
        int half = t >> 7;
        const float* Wsrc = half ? Wn : Ws;
#pragma unroll
        for (int j = 0; j < 16; ++j) {
            short pk[8];
#pragma unroll
            for (int i = 0; i < 8; ++i) {
                int kk = j * 8 + i;
                pk[i] = (short)f2bf(Wsrc[kk * D + n]);
            }
            *(bf16x8*)&Wt[n][half * 128 + j * 8] = *(const bf16x8*)pk;
        }
    }

    // ---- stage Xs[m][k]: k<128 -> fb[v0+m] (copy), k>=128 -> h (convert) ----
    {
        int m = t >> 2;
        int q = t & 3;
        int v = v0 + m;
        int kbase = q * 64;
        if (v < N) {
            if (q < 2) {
                const unsigned short* sp = fb + (size_t)v * D + (q & 1) * 64;
#pragma unroll
                for (int j = 0; j < 8; ++j)
                    *(bf16x8*)&Xs[m][kbase + j * 8] = *(const bf16x8*)(sp + j * 8);
            } else {
                const float* sp = hsrc + (size_t)v * D + (q & 1) * 64;
#pragma unroll
                for (int j = 0; j < 8; ++j) {
                    float4 a = *(const float4*)(sp + j * 8);
                    float4 b = *(const float4*)(sp + j * 8 + 4);
                    short pk[8];
                    pk[0] = (short)f2bf(a.x); pk[1] = (short)f2bf(a.y);
                    pk[2] = (short)f2bf(a.z); pk[3] = (short)f2bf(a.w);
                    pk[4] = (short)f2bf(b.x); pk[5] = (short)f2bf(b.y);
                    pk[6] = (short)f2bf(b.z); pk[7] = (short)f2bf(b.w);
                    *(bf16x8*)&Xs[m][kbase + j * 8] = *(const bf16x8*)pk;
                }
            }
        } else {
            short z[8] = {0, 0, 0, 0, 0, 0, 0, 0};
#pragma unroll
            for (int j = 0; j < 8; ++j)
                *(bf16x8*)&Xs[m][kbase + j * 8] = *(const bf16x8*)z;
        }
    }
    __syncthreads();

    // ---- MFMA main loop ----
    int w    = t >> 6;
    int lane = t & 63;
    int lo16 = lane & 15;
    int quad = lane >> 4;

    f32x4 acc[8];
#pragma unroll
    for (int nt = 0; nt < 8; ++nt) acc[nt] = (f32x4){0.f, 0.f, 0.f, 0.f};

#pragma unroll
    for (int ks = 0; ks < 8; ++ks) {
        bf16x8 a = *(const bf16x8*)&Xs[w * 16 + lo16][ks * 32 + quad * 8];
#pragma unroll
        for (int nt = 0; nt < 8; ++nt) {
            bf16x8 b = *(const bf16x8*)&Wt[nt * 16 + lo16][ks * 32 + quad * 8];
            acc[nt] = __builtin_amdgcn_mfma_f32_16x16x32_bf16(a, b, acc[nt], 0, 0, 0);
        }
    }

    // ---- epilogue: C/D layout col=lane&15, row=quad*4+reg; add bias ----
#pragma unroll
    for (int nt = 0; nt < 8; ++nt) {
        int n = nt * 16 + lo16;
        float bv = bias[n];
#pragma unroll
        for (int r = 0; r < 4; ++r) {
            int row = v0 + w * 16 + quad * 4 + r;
            if (row < N) out[(size_t)row * D + n] = acc[nt][r] + bv;
        }
    }
}

extern "C" void kernel_launch(void* const* d_in, const int* in_sizes, int n_in,
                              void* d_out, int out_size, void* d_ws, size_t ws_size,
                              hipStream_t stream) {
    const float* feat = (const float*)d_in[0];
    const int*   src  = (const int*)d_in[1];
    const int*   dst  = (const int*)d_in[2];
    const float* Ws   = (const float*)d_in[3];
    const float* Wn   = (const float*)d_in[4];
    const float* bias = (const float*)d_in[5];
    float*       out  = (float*)d_out;

    const int N = in_sizes[0] / D;
    const int E = in_sizes[1];
    const int nchunks = (N + SCAN_CHUNK - 1) / SCAN_CHUNK;

    // ws layout: deg[N] | cursor[N] | rs[N] | bsum[64] | bucket[E] | pad | fb[N*D bf16]
    int* deg    = (int*)d_ws;
    int* cursor = deg + N;
    int* rs     = cursor + N;
    int* bsum   = rs + N;
    int* bucket = bsum + 64;
    size_t int_count = (size_t)(3 * N + 64 + E);
    int_count = (int_count + 7) & ~(size_t)7;
    unsigned short* fb = (unsigned short*)((int*)d_ws + int_count);

    float* h = out;   // h_mean staged fp32 in d_out, consumed in-tile by out_mfma

    zero_i32<<<(2 * N + 255) / 256, 256, 0, stream>>>(deg, 2 * N);
    cast_feat_kernel<<<(N * D / 8 + 255) / 256, 256, 0, stream>>>(feat, fb, N * D / 8);
    hist_kernel<<<(E + 255) / 256, 256, 0, stream>>>(dst, deg, E);
    scan1_kernel<<<nchunks, 256, 0, stream>>>(deg, rs, bsum, N);
    scan2_kernel<<<1, 64, 0, stream>>>(bsum, nchunks);
    scan3_kernel<<<(N + 255) / 256, 256, 0, stream>>>(rs, bsum, N);
    fill_kernel<<<(E + 255) / 256, 256, 0, stream>>>(src, dst, cursor, rs, bucket, E);
    gather_kernel<<<(N * 64 + 255) / 256, 256, 0, stream>>>(fb, bucket, rs, deg, h, N);
    out_mfma_kernel<<<(N + 63) / 64, 256, 0, stream>>>(fb, h, Ws, Wn, bias, out, N);
}

// Round 7
// 205.056 us; speedup vs baseline: 4.2846x; 1.2391x over previous
//
#include <hip/hip_runtime.h>

#define D 128
#define EC 4096      // edges per binning block
#define BSH 8        // bin shift: bin = dst >> 8, 256 nodes per bin

typedef __attribute__((ext_vector_type(8))) short bf16x8;
typedef __attribute__((ext_vector_type(4))) float f32x4;

__device__ __forceinline__ unsigned short f2bf(float f) {
    union { float f; unsigned int u; } c;
    c.f = f;
    unsigned int lsb = (c.u >> 16) & 1u;
    c.u += 0x7fffu + lsb;
    return (unsigned short)(c.u >> 16);
}

__device__ __forceinline__ float bf_lo(unsigned int x) {
    union { unsigned int u; float f; } c;
    c.u = x << 16;
    return c.f;
}
__device__ __forceinline__ float bf_hi(unsigned int x) {
    union { unsigned int u; float f; } c;
    c.u = x & 0xffff0000u;
    return c.f;
}

// ---------------------------------------------------------------- zero ints
__global__ __launch_bounds__(256) void zero_i32(int* __restrict__ p, int n) {
    int i = blockIdx.x * 256 + threadIdx.x;
    if (i < n) p[i] = 0;
}

// ---------------------------------------------------------------- cast feat -> bf16
__global__ __launch_bounds__(256) void cast_feat_kernel(const float* __restrict__ feat,
                                                        unsigned short* __restrict__ fb,
                                                        int n8) {
    int i = blockIdx.x * 256 + threadIdx.x;
    if (i >= n8) return;
    const float4* s = (const float4*)(feat + (size_t)i * 8);
    float4 a = s[0];
    float4 b = s[1];
    unsigned short pk[8];
    pk[0] = f2bf(a.x); pk[1] = f2bf(a.y); pk[2] = f2bf(a.z); pk[3] = f2bf(a.w);
    pk[4] = f2bf(b.x); pk[5] = f2bf(b.y); pk[6] = f2bf(b.z); pk[7] = f2bf(b.w);
    *(bf16x8*)(fb + (size_t)i * 8) = *(const bf16x8*)pk;
}

// ---------------------------------------------------------------- bin histogram
// One block per EC-edge chunk; LDS histogram of bins, one global atomic per
// (block,bin) -> ~50K global atomics total instead of 800K.
__global__ __launch_bounds__(256) void binhist_kernel(const int* __restrict__ dst,
                                                      int* __restrict__ bin_cnt,
                                                      int E, int NB) {
    __shared__ int cnt[256];
    int t = threadIdx.x;
    cnt[t] = 0;
    __syncthreads();
    int base = blockIdx.x * EC;
#pragma unroll
    for (int i = 0; i < EC / 256; ++i) {
        int e = base + i * 256 + t;
        if (e < E) atomicAdd(&cnt[dst[e] >> BSH], 1);
    }
    __syncthreads();
    if (t < NB && cnt[t]) atomicAdd(&bin_cnt[t], cnt[t]);
}

// ---------------------------------------------------------------- bin scan
// Exclusive scan of NB (<256) bin counts -> bin_start[0..NB], cursor copy.
__global__ __launch_bounds__(256) void binscan_kernel(const int* __restrict__ bin_cnt,
                                                      int* __restrict__ bin_start,
                                                      int* __restrict__ bin_cursor,
                                                      int NB) {
    __shared__ int lds[256];
    int t = threadIdx.x;
    int v = (t < NB) ? bin_cnt[t] : 0;
    lds[t] = v;
    __syncthreads();
    for (int off = 1; off < 256; off <<= 1) {
        int add = (t >= off) ? lds[t - off] : 0;
        __syncthreads();
        lds[t] += add;
        __syncthreads();
    }
    int ex = lds[t] - v;
    if (t < NB) {
        bin_start[t]  = ex;
        bin_cursor[t] = ex;
        if (t == NB - 1) bin_start[NB] = ex + v;   // = E
    }
}

// ---------------------------------------------------------------- bin scatter
// Same chunking as binhist. Reserve a contiguous range per (block,bin) with
// one global atomic, then place edges via LDS cursors. Edge payload packed:
// low 16 bits = src (N < 65536), bits 16..23 = dst within bin.
__global__ __launch_bounds__(256) void binscatter_kernel(const int* __restrict__ src,
                                                         const int* __restrict__ dst,
                                                         int* __restrict__ bin_cursor,
                                                         unsigned int* __restrict__ ebuf,
                                                         int E, int NB) {
    __shared__ int cnt[256];
    __shared__ int basev[256];
    __shared__ int cur[256];
    int t = threadIdx.x;
    cnt[t] = 0;
    cur[t] = 0;
    __syncthreads();
    int base = blockIdx.x * EC;
#pragma unroll
    for (int i = 0; i < EC / 256; ++i) {
        int e = base + i * 256 + t;
        if (e < E) atomicAdd(&cnt[dst[e] >> BSH], 1);
    }
    __syncthreads();
    if (t < NB && cnt[t]) basev[t] = atomicAdd(&bin_cursor[t], cnt[t]);
    __syncthreads();
#pragma unroll
    for (int i = 0; i < EC / 256; ++i) {
        int e = base + i * 256 + t;
        if (e < E) {
            int d = dst[e];
            int b = d >> BSH;
            int loc = atomicAdd(&cur[b], 1);
            ebuf[basev[b] + loc] =
                (unsigned int)src[e] | ((unsigned int)(d & ((1 << BSH) - 1)) << 16);
        }
    }
}

// ---------------------------------------------------------------- per-bin CSR
// One block per bin. All CSR bookkeeping in LDS (no global atomics); bucket
// writes land in this block's private contiguous segment -> no line bouncing.
__global__ __launch_bounds__(256) void csrbin_kernel(const unsigned int* __restrict__ ebuf,
                                                     const int* __restrict__ bin_start,
                                                     int* __restrict__ rs_g,
                                                     int* __restrict__ deg_g,
                                                     int* __restrict__ bucket, int N) {
    __shared__ int degL[256];
    __shared__ int scn[256];
    __shared__ int cur[256];
    int b = blockIdx.x;
    int t = threadIdx.x;
    int s  = bin_start[b];
    int e2 = bin_start[b + 1];

    degL[t] = 0;
    cur[t]  = 0;
    __syncthreads();
    for (int i = s + t; i < e2; i += 256)
        atomicAdd(&degL[(ebuf[i] >> 16) & 255], 1);
    __syncthreads();

    int v = degL[t];
    scn[t] = v;
    __syncthreads();
    for (int off = 1; off < 256; off <<= 1) {
        int add = (t >= off) ? scn[t - off] : 0;
        __syncthreads();
        scn[t] += add;
        __syncthreads();
    }
    // scn = inclusive; exclusive = scn - degL

    for (int i = s + t; i < e2; i += 256) {
        unsigned int p = ebuf[i];
        int dl = (p >> 16) & 255;
        int sl = atomicAdd(&cur[dl], 1);
        bucket[s + (scn[dl] - degL[dl]) + sl] = (int)(p & 0xffffu);
    }
    __syncthreads();

    int node = (b << BSH) + t;
    if (node < N) {
        rs_g[node]  = s + scn[t] - degL[t];
        deg_g[node] = degL[t];
    }
}

// ---------------------------------------------------------------- gather mean (bf16 rows)
// One wave per node; 4 edges in flight (4 groups x 16 lanes, 16B/lane row
// loads); next bucket index prefetched; shfl_xor cross-group reduce.
__global__ __launch_bounds__(256) void gather_kernel(const unsigned short* __restrict__ fb,
                                                     const int* __restrict__ bucket,
                                                     const int* __restrict__ rs,
                                                     const int* __restrict__ deg,
                                                     float* __restrict__ h, int N) {
    int wid  = (blockIdx.x * 256 + threadIdx.x) >> 6;
    int lane = threadIdx.x & 63;
    if (wid >= N) return;
    int v    = wid;
    int d    = deg[v];
    int base = rs[v];
    int g = lane >> 4;
    int c = lane & 15;

    float acc[8];
#pragma unroll
    for (int j = 0; j < 8; ++j) acc[j] = 0.f;

    int u = (g < d) ? bucket[base + g] : -1;
    for (int i = g; i < d; i += 4) {
        int inext = i + 4;
        int unext = (inext < d) ? bucket[base + inext] : -1;   // prefetch
        const unsigned int* rp = (const unsigned int*)(fb + (size_t)u * D + c * 8);
        uint4 x = *(const uint4*)rp;
        acc[0] += bf_lo(x.x); acc[1] += bf_hi(x.x);
        acc[2] += bf_lo(x.y); acc[3] += bf_hi(x.y);
        acc[4] += bf_lo(x.z); acc[5] += bf_hi(x.z);
        acc[6] += bf_lo(x.w); acc[7] += bf_hi(x.w);
        u = unext;
    }

#pragma unroll
    for (int j = 0; j < 8; ++j) {
        acc[j] += __shfl_xor(acc[j], 16);
        acc[j] += __shfl_xor(acc[j], 32);
    }

    if (g == 0) {
        float inv = (d > 0) ? 1.0f / (float)d : 0.0f;
        float4 o0 = make_float4(acc[0] * inv, acc[1] * inv, acc[2] * inv, acc[3] * inv);
        float4 o1 = make_float4(acc[4] * inv, acc[5] * inv, acc[6] * inv, acc[7] * inv);
        float* op = h + (size_t)v * D + c * 8;
        *(float4*)op = o0;
        *(float4*)(op + 4) = o1;
    }
}

// ---------------------------------------------------------------- MFMA epilogue
// out[M,128] = X[M,256] @ Wcat[256,128] + b, X = [f | h], Wcat = [Ws;Wn].
// LDS: Xs[64][264] + Wt[128][264] bf16 = 101 KB -> 1 block/CU.
// NOTE: hsrc aliases out (h staged in d_out); each block reads only its own
// rows into LDS before storing — no cross-block aliasing.
#define KX 256
#define XP 8
__global__ __launch_bounds__(256) void out_mfma_kernel(const unsigned short* __restrict__ fb,
                                                       const float* hsrc,
                                                       const float* __restrict__ Ws,
                                                       const float* __restrict__ Wn,
                                                       const float* __restrict__ bias,
                                                       float* out, int N) {
    __shared__ short Xs[64][KX + XP];
    __shared__ short Wt[128][KX + XP];

    int t  = threadIdx.x;
    int v0 = blockIdx.x * 64;

    // ---- stage Wt[n][k] = Wcat[k][n] as bf16 ----
    {
        int n    = t & 127;
        int half = t >> 7;
        const float* Wsrc = half ? Wn : Ws;
#pragma unroll
        for (int j = 0; j < 16; ++j) {
            short pk[8];
#pragma unroll
            for (int i = 0; i < 8; ++i) {
                int kk = j * 8 + i;
                pk[i] = (short)f2bf(Wsrc[kk * D + n]);
            }
            *(bf16x8*)&Wt[n][half * 128 + j * 8] = *(const bf16x8*)pk;
        }
    }

    // ---- stage Xs[m][k]: k<128 -> fb copy, k>=128 -> h convert ----
    {
        int m = t >> 2;
        int q = t & 3;
        int v = v0 + m;
        int kbase = q * 64;
        if (v < N) {
            if (q < 2) {
                const unsigned short* sp = fb + (size_t)v * D + (q & 1) * 64;
#pragma unroll
                for (int j = 0; j < 8; ++j)
                    *(bf16x8*)&Xs[m][kbase + j * 8] = *(const bf16x8*)(sp + j * 8);
            } else {
                const float* sp = hsrc + (size_t)v * D + (q & 1) * 64;
#pragma unroll
                for (int j = 0; j < 8; ++j) {
                    float4 a = *(const float4*)(sp + j * 8);
                    float4 b = *(const float4*)(sp + j * 8 + 4);
                    short pk[8];
                    pk[0] = (short)f2bf(a.x); pk[1] = (short)f2bf(a.y);
                    pk[2] = (short)f2bf(a.z); pk[3] = (short)f2bf(a.w);
                    pk[4] = (short)f2bf(b.x); pk[5] = (short)f2bf(b.y);
                    pk[6] = (short)f2bf(b.z); pk[7] = (short)f2bf(b.w);
                    *(bf16x8*)&Xs[m][kbase + j * 8] = *(const bf16x8*)pk;
                }
            }
        } else {
            short z[8] = {0, 0, 0, 0, 0, 0, 0, 0};
#pragma unroll
            for (int j = 0; j < 8; ++j)
                *(bf16x8*)&Xs[m][kbase + j * 8] = *(const bf16x8*)z;
        }
    }
    __syncthreads();

    // ---- MFMA main loop ----
    int w    = t >> 6;
    int lane = t & 63;
    int lo16 = lane & 15;
    int quad = lane >> 4;

    f32x4 acc[8];
#pragma unroll
    for (int nt = 0; nt < 8; ++nt) acc[nt] = (f32x4){0.f, 0.f, 0.f, 0.f};

#pragma unroll
    for (int ks = 0; ks < 8; ++ks) {
        bf16x8 a = *(const bf16x8*)&Xs[w * 16 + lo16][ks * 32 + quad * 8];
#pragma unroll
        for (int nt = 0; nt < 8; ++nt) {
            bf16x8 b = *(const bf16x8*)&Wt[nt * 16 + lo16][ks * 32 + quad * 8];
            acc[nt] = __builtin_amdgcn_mfma_f32_16x16x32_bf16(a, b, acc[nt], 0, 0, 0);
        }
    }

    // ---- epilogue: C/D layout col=lane&15, row=quad*4+reg; add bias ----
#pragma unroll
    for (int nt = 0; nt < 8; ++nt) {
        int n = nt * 16 + lo16;
        float bv = bias[n];
#pragma unroll
        for (int r = 0; r < 4; ++r) {
            int row = v0 + w * 16 + quad * 4 + r;
            if (row < N) out[(size_t)row * D + n] = acc[nt][r] + bv;
        }
    }
}

extern "C" void kernel_launch(void* const* d_in, const int* in_sizes, int n_in,
                              void* d_out, int out_size, void* d_ws, size_t ws_size,
                              hipStream_t stream) {
    const float* feat = (const float*)d_in[0];
    const int*   src  = (const int*)d_in[1];
    const int*   dst  = (const int*)d_in[2];
    const float* Ws   = (const float*)d_in[3];
    const float* Wn   = (const float*)d_in[4];
    const float* bias = (const float*)d_in[5];
    float*       out  = (float*)d_out;

    const int N  = in_sizes[0] / D;
    const int E  = in_sizes[1];
    const int NB = (N + (1 << BSH) - 1) >> BSH;      // bins of 256 nodes
    const int nchunk = (E + EC - 1) / EC;

    // ws layout (ints): bin_cnt[256] | bin_start[260] | bin_cursor[256] |
    //                   rs[N] | deg[N] | ebuf[E] | bucket[E] | pad | fb[N*D bf16]
    int* bin_cnt    = (int*)d_ws;
    int* bin_start  = bin_cnt + 256;
    int* bin_cursor = bin_start + 260;
    int* rs         = bin_cursor + 256;
    int* deg        = rs + N;
    unsigned int* ebuf = (unsigned int*)(deg + N);
    int* bucket     = (int*)(ebuf + E);
    size_t int_count = (size_t)(772 + 2 * N + 2 * E);
    int_count = (int_count + 7) & ~(size_t)7;
    unsigned short* fb = (unsigned short*)((int*)d_ws + int_count);

    float* h = out;   // h_mean staged fp32 in d_out, consumed in-tile by out_mfma

    zero_i32<<<1, 256, 0, stream>>>(bin_cnt, 256);
    cast_feat_kernel<<<(N * D / 8 + 255) / 256, 256, 0, stream>>>(feat, fb, N * D / 8);
    binhist_kernel<<<nchunk, 256, 0, stream>>>(dst, bin_cnt, E, NB);
    binscan_kernel<<<1, 256, 0, stream>>>(bin_cnt, bin_start, bin_cursor, NB);
    binscatter_kernel<<<nchunk, 256, 0, stream>>>(src, dst, bin_cursor, ebuf, E, NB);
    csrbin_kernel<<<NB, 256, 0, stream>>>(ebuf, bin_start, rs, deg, bucket, N);
    gather_kernel<<<(N * 64 + 255) / 256, 256, 0, stream>>>(fb, bucket, rs, deg, h, N);
    out_mfma_kernel<<<(N + 63) / 64, 256, 0, stream>>>(fb, h, Ws, Wn, bias, out, N);
}

// Round 8
// 194.569 us; speedup vs baseline: 4.5156x; 1.0539x over previous
//
#include <hip/hip_runtime.h>

#define D 128
#define EC 4096      // edges per binning block
#define BSH 8        // bin shift: bin = dst >> 8, 256 nodes per bin

typedef __attribute__((ext_vector_type(8))) short bf16x8;
typedef __attribute__((ext_vector_type(4))) float f32x4;

__device__ __forceinline__ unsigned short f2bf(float f) {
    union { float f; unsigned int u; } c;
    c.f = f;
    unsigned int lsb = (c.u >> 16) & 1u;
    c.u += 0x7fffu + lsb;
    return (unsigned short)(c.u >> 16);
}

__device__ __forceinline__ float bf_lo(unsigned int x) {
    union { unsigned int u; float f; } c;
    c.u = x << 16;
    return c.f;
}
__device__ __forceinline__ float bf_hi(unsigned int x) {
    union { unsigned int u; float f; } c;
    c.u = x & 0xffff0000u;
    return c.f;
}

// ---------------------------------------------------------------- zero ints
__global__ __launch_bounds__(256) void zero_i32(int* __restrict__ p, int n) {
    int i = blockIdx.x * 256 + threadIdx.x;
    if (i < n) p[i] = 0;
}

// ---------------------------------------------------------------- cast feat -> bf16
__global__ __launch_bounds__(256) void cast_feat_kernel(const float* __restrict__ feat,
                                                        unsigned short* __restrict__ fb,
                                                        int n8) {
    int i = blockIdx.x * 256 + threadIdx.x;
    if (i >= n8) return;
    const float4* s = (const float4*)(feat + (size_t)i * 8);
    float4 a = s[0];
    float4 b = s[1];
    unsigned short pk[8];
    pk[0] = f2bf(a.x); pk[1] = f2bf(a.y); pk[2] = f2bf(a.z); pk[3] = f2bf(a.w);
    pk[4] = f2bf(b.x); pk[5] = f2bf(b.y); pk[6] = f2bf(b.z); pk[7] = f2bf(b.w);
    *(bf16x8*)(fb + (size_t)i * 8) = *(const bf16x8*)pk;
}

// ---------------------------------------------------------------- W -> fragment order
// Wfrag[((nt*8+ks)*64 + lane)*8 + j] = bf16(Wcat[ks*32 + quad*8 + j][nt*16 + lo16])
// so a wave's B-frag load for (ks,nt) is one contiguous, coalesced 1KB read.
__global__ __launch_bounds__(256) void prep_w_kernel(const float* __restrict__ Ws,
                                                     const float* __restrict__ Wn,
                                                     unsigned short* __restrict__ Wfrag) {
    int tid = blockIdx.x * 256 + threadIdx.x;      // 0..4095
    if (tid >= 4096) return;
    int l  = tid & 63;
    int ks = (tid >> 6) & 7;
    int nt = tid >> 9;
    int n    = nt * 16 + (l & 15);
    int kb   = ks * 32 + (l >> 4) * 8;
    unsigned short pk[8];
#pragma unroll
    for (int j = 0; j < 8; ++j) {
        int k = kb + j;
        float w = (k < 128) ? Ws[k * D + n] : Wn[(k - 128) * D + n];
        pk[j] = f2bf(w);
    }
    *(bf16x8*)(Wfrag + (size_t)tid * 8) = *(const bf16x8*)pk;
}

// ---------------------------------------------------------------- bin histogram
__global__ __launch_bounds__(256) void binhist_kernel(const int* __restrict__ dst,
                                                      int* __restrict__ bin_cnt,
                                                      int E, int NB) {
    __shared__ int cnt[256];
    int t = threadIdx.x;
    cnt[t] = 0;
    __syncthreads();
    int base = blockIdx.x * EC;
#pragma unroll
    for (int i = 0; i < EC / 256; ++i) {
        int e = base + i * 256 + t;
        if (e < E) atomicAdd(&cnt[dst[e] >> BSH], 1);
    }
    __syncthreads();
    if (t < NB && cnt[t]) atomicAdd(&bin_cnt[t], cnt[t]);
}

// ---------------------------------------------------------------- bin scan
__global__ __launch_bounds__(256) void binscan_kernel(const int* __restrict__ bin_cnt,
                                                      int* __restrict__ bin_start,
                                                      int* __restrict__ bin_cursor,
                                                      int NB) {
    __shared__ int lds[256];
    int t = threadIdx.x;
    int v = (t < NB) ? bin_cnt[t] : 0;
    lds[t] = v;
    __syncthreads();
    for (int off = 1; off < 256; off <<= 1) {
        int add = (t >= off) ? lds[t - off] : 0;
        __syncthreads();
        lds[t] += add;
        __syncthreads();
    }
    int ex = lds[t] - v;
    if (t < NB) {
        bin_start[t]  = ex;
        bin_cursor[t] = ex;
        if (t == NB - 1) bin_start[NB] = ex + v;
    }
}

// ---------------------------------------------------------------- bin scatter
__global__ __launch_bounds__(256) void binscatter_kernel(const int* __restrict__ src,
                                                         const int* __restrict__ dst,
                                                         int* __restrict__ bin_cursor,
                                                         unsigned int* __restrict__ ebuf,
                                                         int E, int NB) {
    __shared__ int cnt[256];
    __shared__ int basev[256];
    __shared__ int cur[256];
    int t = threadIdx.x;
    cnt[t] = 0;
    cur[t] = 0;
    __syncthreads();
    int base = blockIdx.x * EC;
#pragma unroll
    for (int i = 0; i < EC / 256; ++i) {
        int e = base + i * 256 + t;
        if (e < E) atomicAdd(&cnt[dst[e] >> BSH], 1);
    }
    __syncthreads();
    if (t < NB && cnt[t]) basev[t] = atomicAdd(&bin_cursor[t], cnt[t]);
    __syncthreads();
#pragma unroll
    for (int i = 0; i < EC / 256; ++i) {
        int e = base + i * 256 + t;
        if (e < E) {
            int d = dst[e];
            int b = d >> BSH;
            int loc = atomicAdd(&cur[b], 1);
            ebuf[basev[b] + loc] =
                (unsigned int)src[e] | ((unsigned int)(d & ((1 << BSH) - 1)) << 16);
        }
    }
}

// ---------------------------------------------------------------- per-bin CSR
__global__ __launch_bounds__(256) void csrbin_kernel(const unsigned int* __restrict__ ebuf,
                                                     const int* __restrict__ bin_start,
                                                     int* __restrict__ rs_g,
                                                     int* __restrict__ deg_g,
                                                     int* __restrict__ bucket, int N) {
    __shared__ int degL[256];
    __shared__ int scn[256];
    __shared__ int cur[256];
    int b = blockIdx.x;
    int t = threadIdx.x;
    int s  = bin_start[b];
    int e2 = bin_start[b + 1];

    degL[t] = 0;
    cur[t]  = 0;
    __syncthreads();
    for (int i = s + t; i < e2; i += 256)
        atomicAdd(&degL[(ebuf[i] >> 16) & 255], 1);
    __syncthreads();

    int v = degL[t];
    scn[t] = v;
    __syncthreads();
    for (int off = 1; off < 256; off <<= 1) {
        int add = (t >= off) ? scn[t - off] : 0;
        __syncthreads();
        scn[t] += add;
        __syncthreads();
    }

    for (int i = s + t; i < e2; i += 256) {
        unsigned int p = ebuf[i];
        int dl = (p >> 16) & 255;
        int sl = atomicAdd(&cur[dl], 1);
        bucket[s + (scn[dl] - degL[dl]) + sl] = (int)(p & 0xffffu);
    }
    __syncthreads();

    int node = (b << BSH) + t;
    if (node < N) {
        rs_g[node]  = s + scn[t] - degL[t];
        deg_g[node] = degL[t];
    }
}

// ---------------------------------------------------------------- gather mean (bf16 out)
// One wave per node; 4 edges in flight (4 groups x 16 lanes, 16B/lane row
// loads); next bucket index prefetched; shfl_xor reduce; group 0 writes the
// mean row as bf16 (16B/lane) into hb.
__global__ __launch_bounds__(256) void gather_kernel(const unsigned short* __restrict__ fb,
                                                     const int* __restrict__ bucket,
                                                     const int* __restrict__ rs,
                                                     const int* __restrict__ deg,
                                                     unsigned short* __restrict__ hb, int N) {
    int wid  = (blockIdx.x * 256 + threadIdx.x) >> 6;
    int lane = threadIdx.x & 63;
    if (wid >= N) return;
    int v    = wid;
    int d    = deg[v];
    int base = rs[v];
    int g = lane >> 4;
    int c = lane & 15;

    float acc[8];
#pragma unroll
    for (int j = 0; j < 8; ++j) acc[j] = 0.f;

    int u = (g < d) ? bucket[base + g] : -1;
    for (int i = g; i < d; i += 4) {
        int inext = i + 4;
        int unext = (inext < d) ? bucket[base + inext] : -1;   // prefetch
        const unsigned int* rp = (const unsigned int*)(fb + (size_t)u * D + c * 8);
        uint4 x = *(const uint4*)rp;
        acc[0] += bf_lo(x.x); acc[1] += bf_hi(x.x);
        acc[2] += bf_lo(x.y); acc[3] += bf_hi(x.y);
        acc[4] += bf_lo(x.z); acc[5] += bf_hi(x.z);
        acc[6] += bf_lo(x.w); acc[7] += bf_hi(x.w);
        u = unext;
    }

#pragma unroll
    for (int j = 0; j < 8; ++j) {
        acc[j] += __shfl_xor(acc[j], 16);
        acc[j] += __shfl_xor(acc[j], 32);
    }

    if (g == 0) {
        float inv = (d > 0) ? 1.0f / (float)d : 0.0f;
        unsigned short pk[8];
#pragma unroll
        for (int j = 0; j < 8; ++j) pk[j] = f2bf(acc[j] * inv);
        *(bf16x8*)(hb + (size_t)v * D + c * 8) = *(const bf16x8*)pk;
    }
}

// ---------------------------------------------------------------- MFMA epilogue (no LDS)
// out[M,128] = X[M,256] @ Wcat[256,128] + b; X = [fb | hb] (both bf16 tables).
// Block = 4 waves, 64 rows; wave w owns rows [v0+w*16, +16).
// A-frags straight from fb/hb (per ks: 16 consecutive rows x 64B, reused over
// 8 nt); B-frags from Wfrag (contiguous 1KB coalesced per (ks,nt), L2-hot).
// No LDS, no barriers, no conversions. Tail rows clamp to N-1, stores guarded.
__global__ __launch_bounds__(256) void out_mfma_kernel(const unsigned short* __restrict__ fb,
                                                       const unsigned short* __restrict__ hb,
                                                       const unsigned short* __restrict__ Wfrag,
                                                       const float* __restrict__ bias,
                                                       float* __restrict__ out, int N) {
    int t    = threadIdx.x;
    int w    = t >> 6;
    int lane = t & 63;
    int lo16 = lane & 15;
    int quad = lane >> 4;
    int v0   = blockIdx.x * 64;

    int rowA = v0 + w * 16 + lo16;
    if (rowA > N - 1) rowA = N - 1;                 // clamp; stores guarded below

    f32x4 acc[8];
#pragma unroll
    for (int nt = 0; nt < 8; ++nt) acc[nt] = (f32x4){0.f, 0.f, 0.f, 0.f};

#pragma unroll
    for (int ks = 0; ks < 8; ++ks) {
        const unsigned short* xsrc = (ks < 4)
            ? fb + (size_t)rowA * D + ks * 32 + quad * 8
            : hb + (size_t)rowA * D + (ks - 4) * 32 + quad * 8;
        bf16x8 a = *(const bf16x8*)xsrc;
        const unsigned short* wp = Wfrag + ((size_t)ks * 64 + lane) * 8;
#pragma unroll
        for (int nt = 0; nt < 8; ++nt) {
            bf16x8 b = *(const bf16x8*)(wp + (size_t)nt * 8 * 64 * 8);
            acc[nt] = __builtin_amdgcn_mfma_f32_16x16x32_bf16(a, b, acc[nt], 0, 0, 0);
        }
    }

    // C/D layout: col = lane&15, row = quad*4 + reg
#pragma unroll
    for (int nt = 0; nt < 8; ++nt) {
        int n = nt * 16 + lo16;
        float bv = bias[n];
#pragma unroll
        for (int r = 0; r < 4; ++r) {
            int row = v0 + w * 16 + quad * 4 + r;
            if (row < N) out[(size_t)row * D + n] = acc[nt][r] + bv;
        }
    }
}

extern "C" void kernel_launch(void* const* d_in, const int* in_sizes, int n_in,
                              void* d_out, int out_size, void* d_ws, size_t ws_size,
                              hipStream_t stream) {
    const float* feat = (const float*)d_in[0];
    const int*   src  = (const int*)d_in[1];
    const int*   dst  = (const int*)d_in[2];
    const float* Ws   = (const float*)d_in[3];
    const float* Wn   = (const float*)d_in[4];
    const float* bias = (const float*)d_in[5];
    float*       out  = (float*)d_out;

    const int N  = in_sizes[0] / D;
    const int E  = in_sizes[1];
    const int NB = (N + (1 << BSH) - 1) >> BSH;      // bins of 256 nodes
    const int nchunk = (E + EC - 1) / EC;

    // ws layout (ints): bin_cnt[256] | bin_start[260] | bin_cursor[256] |
    //   rs[N] | deg[N] | ebuf[E] | bucket[E] | pad | fb[N*D] | hb[N*D] | Wfrag[32768] (bf16)
    int* bin_cnt    = (int*)d_ws;
    int* bin_start  = bin_cnt + 256;
    int* bin_cursor = bin_start + 260;
    int* rs         = bin_cursor + 256;
    int* deg        = rs + N;
    unsigned int* ebuf = (unsigned int*)(deg + N);
    int* bucket     = (int*)(ebuf + E);
    size_t int_count = (size_t)(772 + 2 * N + 2 * E);
    int_count = (int_count + 7) & ~(size_t)7;
    unsigned short* fb    = (unsigned short*)((int*)d_ws + int_count);
    unsigned short* hb    = fb + (size_t)N * D;
    unsigned short* Wfrag = hb + (size_t)N * D;

    zero_i32<<<1, 256, 0, stream>>>(bin_cnt, 256);
    cast_feat_kernel<<<(N * D / 8 + 255) / 256, 256, 0, stream>>>(feat, fb, N * D / 8);
    prep_w_kernel<<<16, 256, 0, stream>>>(Ws, Wn, Wfrag);
    binhist_kernel<<<nchunk, 256, 0, stream>>>(dst, bin_cnt, E, NB);
    binscan_kernel<<<1, 256, 0, stream>>>(bin_cnt, bin_start, bin_cursor, NB);
    binscatter_kernel<<<nchunk, 256, 0, stream>>>(src, dst, bin_cursor, ebuf, E, NB);
    csrbin_kernel<<<NB, 256, 0, stream>>>(ebuf, bin_start, rs, deg, bucket, N);
    gather_kernel<<<(N * 64 + 255) / 256, 256, 0, stream>>>(fb, bucket, rs, deg, hb, N);
    out_mfma_kernel<<<(N + 63) / 64, 256, 0, stream>>>(fb, hb, Wfrag, bias, out, N);
}